// Round 3
// baseline (1986.902 us; speedup 1.0000x reference)
//
#include <hip/hip_runtime.h>
#include <hip/hip_bf16.h>

#define N_NODES 100000
#define N_EDGES 1600000
#define DIM_IN  256
#define DIM_H   128

// ------------------------------------------------- edge_index width detect
// int64 indices in [0,1e5) have all-zero odd 32-bit words; int32 edge data
// has ~0 probability of 512 consecutive zero odd words. flag=1 -> int64.
__global__ __launch_bounds__(1024) void k_detect(const int* __restrict__ e,
                                                 int* __restrict__ flag) {
  __shared__ int s;
  if (threadIdx.x == 0) s = 0;
  __syncthreads();
  atomicOr(&s, e[2 * threadIdx.x + 1]);
  __syncthreads();
  if (threadIdx.x == 0) *flag = (s == 0) ? 1 : 0;
}

__device__ __forceinline__ int get_src(const int* e, int is64, int i) {
  return is64 ? e[2 * i] : e[i];
}
__device__ __forceinline__ int get_dst(const int* e, int is64, int i) {
  return is64 ? e[2 * (N_EDGES + i)] : e[N_EDGES + i];
}

// ---------------------------------------------------------------- degree
__global__ __launch_bounds__(256) void k_deg_init(float* __restrict__ deg) {
  int i = blockIdx.x * 256 + threadIdx.x;
  if (i < N_NODES) deg[i] = 1.0f;  // self-loop contributes 1
}

__global__ __launch_bounds__(256) void k_deg_acc(const int* __restrict__ eidx,
                                                 const int* __restrict__ flag,
                                                 float* __restrict__ deg) {
  int e = blockIdx.x * 256 + threadIdx.x;
  int is64 = *flag;
  if (e < N_EDGES) {
    unsigned d = (unsigned)get_dst(eidx, is64, e);
    if (d < N_NODES) unsafeAtomicAdd(&deg[d], 1.0f);
  }
}

__global__ __launch_bounds__(256) void k_dinv(float* __restrict__ deg) {
  int i = blockIdx.x * 256 + threadIdx.x;
  if (i < N_NODES) deg[i] = rsqrtf(deg[i]);
}

// ---------------------------------------------------------------- loader
__device__ __forceinline__ void load8(const float* p, float* o) {
  float4 a = reinterpret_cast<const float4*>(p)[0];
  float4 b = reinterpret_cast<const float4*>(p)[1];
  o[0] = a.x; o[1] = a.y; o[2] = a.z; o[3] = a.w;
  o[4] = b.x; o[5] = b.y; o[6] = b.z; o[7] = b.w;
}

// ---------------------------------------------------------------- GEMM
// C[M,128] = A[M,K] @ B[K,128] (+bias, optional relu). Block tile 64x128,
// 256 threads, each thread 4 rows x 8 cols. A staged in LDS, B L1/L2-hot.
template <int K>
__global__ __launch_bounds__(256)
void k_gemm(const float* __restrict__ A, const float* __restrict__ B,
            const float* __restrict__ bias, float* __restrict__ C,
            const int do_relu) {
  __shared__ float As[64][33];
  const int tid = threadIdx.x;
  const int tx = tid & 15;   // col group: cols tx*8 .. tx*8+7
  const int ty = tid >> 4;   // row group: rows ty*4 .. ty*4+3
  const int m0 = blockIdx.x * 64;

  float acc[4][8];
#pragma unroll
  for (int i = 0; i < 4; ++i)
#pragma unroll
    for (int j = 0; j < 8; ++j) acc[i][j] = 0.f;

  const int rs = tid >> 2;        // staging row 0..63
  const int ks = (tid & 3) * 8;   // staging k-chunk

  for (int k0 = 0; k0 < K; k0 += 32) {
    float av8[8];
    const int gm = m0 + rs;
    if (gm < N_NODES) {
      load8(&A[(size_t)gm * K + k0 + ks], av8);
    } else {
#pragma unroll
      for (int j = 0; j < 8; ++j) av8[j] = 0.f;
    }
    __syncthreads();
#pragma unroll
    for (int j = 0; j < 8; ++j) As[rs][ks + j] = av8[j];
    __syncthreads();

    const float* Bp = B + (size_t)k0 * DIM_H + tx * 8;
#pragma unroll 4
    for (int k = 0; k < 32; ++k) {
      float bv[8];
      load8(Bp + (size_t)k * DIM_H, bv);
      float av[4];
#pragma unroll
      for (int rr = 0; rr < 4; ++rr) av[rr] = As[ty * 4 + rr][k];
#pragma unroll
      for (int rr = 0; rr < 4; ++rr)
#pragma unroll
        for (int cc = 0; cc < 8; ++cc)
          acc[rr][cc] = fmaf(av[rr], bv[cc], acc[rr][cc]);
    }
  }

  float bs[8];
  if (bias) {
    load8(bias + tx * 8, bs);
  } else {
#pragma unroll
    for (int j = 0; j < 8; ++j) bs[j] = 0.f;
  }
#pragma unroll
  for (int rr = 0; rr < 4; ++rr) {
    const int gm = m0 + ty * 4 + rr;
    if (gm < N_NODES) {
      float v[8];
#pragma unroll
      for (int cc = 0; cc < 8; ++cc) {
        float t = acc[rr][cc] + bs[cc];
        v[cc] = do_relu ? fmaxf(t, 0.f) : t;
      }
      float* Cp = &C[(size_t)gm * DIM_H + tx * 8];
      reinterpret_cast<float4*>(Cp)[0] = make_float4(v[0], v[1], v[2], v[3]);
      reinterpret_cast<float4*>(Cp)[1] = make_float4(v[4], v[5], v[6], v[7]);
    }
  }
}

// ---------------------------------------------------------------- aggregation
// h[i][c] = bias[c] + dinv[i]^2 * t[i][c]   (bias + self-loop term)
__global__ __launch_bounds__(256)
void k_aggr_init(const float* __restrict__ t, const float* __restrict__ dinv,
                 const float* __restrict__ bias, float* __restrict__ h) {
  int idx = blockIdx.x * 256 + threadIdx.x;
  if (idx < N_NODES * DIM_H) {
    int i = idx >> 7;
    int c = idx & 127;
    float d = dinv[i];
    h[idx] = bias[c] + t[idx] * d * d;
  }
}

// h[dst] += t[src] * dinv[src]*dinv[dst], 128 lanes per edge, 2 edges/block
__global__ __launch_bounds__(256)
void k_aggr_edges(const int* __restrict__ eidx, const int* __restrict__ flag,
                  const float* __restrict__ t, const float* __restrict__ dinv,
                  float* __restrict__ h) {
  int e = blockIdx.x * 2 + (threadIdx.x >> 7);
  int c = threadIdx.x & 127;
  int is64 = *flag;
  if (e < N_EDGES) {
    unsigned s = (unsigned)get_src(eidx, is64, e);
    unsigned d = (unsigned)get_dst(eidx, is64, e);
    if (s < N_NODES && d < N_NODES) {
      float nrm = dinv[s] * dinv[d];
      unsafeAtomicAdd(&h[(size_t)d * DIM_H + c], t[(size_t)s * DIM_H + c] * nrm);
    }
  }
}

// ---------------------------------------------------------------- head
// out[i,:] = h[i,:] @ Wh + bh ; one wave per node, float32 output
__global__ __launch_bounds__(256)
void k_head(const float* __restrict__ h, const float* __restrict__ Wh,
            const float* __restrict__ bh, float* __restrict__ out) {
  int node = blockIdx.x * 4 + (threadIdx.x >> 6);
  int lane = threadIdx.x & 63;
  if (node >= N_NODES) return;
  float h0 = h[(size_t)node * DIM_H + lane];
  float h1 = h[(size_t)node * DIM_H + 64 + lane];
  float s0 = h0 * Wh[lane * 2 + 0] + h1 * Wh[(lane + 64) * 2 + 0];
  float s1 = h0 * Wh[lane * 2 + 1] + h1 * Wh[(lane + 64) * 2 + 1];
#pragma unroll
  for (int off = 32; off > 0; off >>= 1) {
    s0 += __shfl_down(s0, off);
    s1 += __shfl_down(s1, off);
  }
  if (lane == 0) {
    reinterpret_cast<float2*>(out)[node] = make_float2(s0 + bh[0], s1 + bh[1]);
  }
}

// ---------------------------------------------------------------- launch
extern "C" void kernel_launch(void* const* d_in, const int* in_sizes, int n_in,
                              void* d_out, int out_size, void* d_ws, size_t ws_size,
                              hipStream_t stream) {
  (void)in_sizes; (void)n_in; (void)out_size; (void)ws_size;
  const int* eidx = (const int*)d_in[0];
  const float* x  = (const float*)d_in[1];
  const float* Wi = (const float*)d_in[2];
  const float* bi = (const float*)d_in[3];
  const float* W1 = (const float*)d_in[4];
  const float* b1 = (const float*)d_in[5];
  const float* W2 = (const float*)d_in[6];
  const float* b2 = (const float*)d_in[7];
  const float* Wh = (const float*)d_in[8];
  const float* bh = (const float*)d_in[9];
  float* out = (float*)d_out;

  // workspace layout (~103 MB):
  //   [0, 4096)              flag (int) + pad
  //   [4096, 405504)         dinv (N floats, padded)
  //   [405504, 51605504)     bufA: N x 128 f32
  //   [51605504, 102805504)  bufB: N x 128 f32
  char* ws = (char*)d_ws;
  int*   flag = (int*)ws;
  float* dinv = (float*)(ws + 4096);
  float* bufA = (float*)(ws + 405504);
  float* bufB = (float*)(ws + 51605504);

  const int gN   = (N_NODES + 255) / 256;
  const int gE   = (N_EDGES + 255) / 256;
  const int gM   = (N_NODES + 63) / 64;
  const int gNH  = (N_NODES * DIM_H + 255) / 256;
  const int gE2  = (N_EDGES + 1) / 2;
  const int gHd  = (N_NODES + 3) / 4;

  // edge width detect + degree + normalization
  k_detect<<<1, 1024, 0, stream>>>(eidx, flag);
  k_deg_init<<<gN, 256, 0, stream>>>(dinv);
  k_deg_acc<<<gE, 256, 0, stream>>>(eidx, flag, dinv);
  k_dinv<<<gN, 256, 0, stream>>>(dinv);

  // h1 = relu(x @ Wi + bi)
  k_gemm<DIM_IN><<<gM, 256, 0, stream>>>(x, Wi, bi, bufA, 1);

  // layer 1: t = h1 @ W1 ; h2 = scatter(t) + b1
  k_gemm<DIM_H><<<gM, 256, 0, stream>>>(bufA, W1, nullptr, bufB, 0);
  k_aggr_init<<<gNH, 256, 0, stream>>>(bufB, dinv, b1, bufA);
  k_aggr_edges<<<gE2, 256, 0, stream>>>(eidx, flag, bufB, dinv, bufA);

  // layer 2
  k_gemm<DIM_H><<<gM, 256, 0, stream>>>(bufA, W2, nullptr, bufB, 0);
  k_aggr_init<<<gNH, 256, 0, stream>>>(bufB, dinv, b2, bufA);
  k_aggr_edges<<<gE2, 256, 0, stream>>>(eidx, flag, bufB, dinv, bufA);

  // head
  k_head<<<gHd, 256, 0, stream>>>(bufA, Wh, bh, out);
}

// Round 4
// 1067.660 us; speedup vs baseline: 1.8610x; 1.8610x over previous
//
#include <hip/hip_runtime.h>
#include <hip/hip_bf16.h>

#define N_NODES 100000
#define N_EDGES 1600000
#define DIM_IN  256
#define DIM_H   128

// ------------------------------------------------- edge_index width detect
// int64 indices in [0,1e5) have all-zero odd 32-bit words; int32 edge data
// has ~0 probability of 1024 consecutive zero odd words. flag=1 -> int64.
__global__ __launch_bounds__(1024) void k_detect(const int* __restrict__ e,
                                                 int* __restrict__ flag) {
  __shared__ int s;
  if (threadIdx.x == 0) s = 0;
  __syncthreads();
  atomicOr(&s, e[2 * threadIdx.x + 1]);
  __syncthreads();
  if (threadIdx.x == 0) *flag = (s == 0) ? 1 : 0;
}

__device__ __forceinline__ int get_src(const int* e, int is64, int i) {
  return is64 ? e[2 * i] : e[i];
}
__device__ __forceinline__ int get_dst(const int* e, int is64, int i) {
  return is64 ? e[2 * (N_EDGES + i)] : e[N_EDGES + i];
}

// ---------------------------------------------------------------- degree/CSR
__global__ __launch_bounds__(256) void k_zero(int* __restrict__ p, int n) {
  int i = blockIdx.x * 256 + threadIdx.x;
  if (i < n) p[i] = 0;
}

// in-degree histogram (excluding self-loop) into off[]
__global__ __launch_bounds__(256) void k_count(const int* __restrict__ eidx,
                                               const int* __restrict__ flag,
                                               int* __restrict__ off) {
  int e = blockIdx.x * 256 + threadIdx.x;
  int is64 = *flag;
  if (e < N_EDGES) {
    unsigned d = (unsigned)get_dst(eidx, is64, e);
    if (d < N_NODES) atomicAdd(&off[d], 1);
  }
}

// dinv[i] = rsqrt(1 + indegree)  (self-loop adds 1)
__global__ __launch_bounds__(256) void k_dinv(const int* __restrict__ off,
                                              float* __restrict__ dinv) {
  int i = blockIdx.x * 256 + threadIdx.x;
  if (i < N_NODES) dinv[i] = rsqrtf(1.0f + (float)off[i]);
}

// single-block exclusive prefix sum of off[0..N) in place
__global__ __launch_bounds__(1024) void k_scan(int* __restrict__ off) {
  __shared__ int part[1024];
  const int C = (N_NODES + 1023) / 1024;
  int t = threadIdx.x;
  int lo = t * C, hi = min(lo + C, N_NODES);
  int s = 0;
  for (int i = lo; i < hi; ++i) s += off[i];
  part[t] = s;
  __syncthreads();
  for (int d = 1; d < 1024; d <<= 1) {
    int v = (t >= d) ? part[t - d] : 0;
    __syncthreads();
    part[t] += v;
    __syncthreads();
  }
  int base = (t == 0) ? 0 : part[t - 1];
  for (int i = lo; i < hi; ++i) {
    int c = off[i];
    off[i] = base;
    base += c;
  }
}

// scatter src ids into CSR; converts off[] from starts to ends
__global__ __launch_bounds__(256) void k_fill(const int* __restrict__ eidx,
                                              const int* __restrict__ flag,
                                              int* __restrict__ off,
                                              int* __restrict__ csr) {
  int e = blockIdx.x * 256 + threadIdx.x;
  int is64 = *flag;
  if (e < N_EDGES) {
    unsigned s = (unsigned)get_src(eidx, is64, e);
    unsigned d = (unsigned)get_dst(eidx, is64, e);
    if (s < N_NODES && d < N_NODES) {
      int pos = atomicAdd(&off[d], 1);
      csr[pos] = (int)s;
    }
  }
}

// ---------------------------------------------------------------- loader
__device__ __forceinline__ void load8(const float* p, float* o) {
  float4 a = reinterpret_cast<const float4*>(p)[0];
  float4 b = reinterpret_cast<const float4*>(p)[1];
  o[0] = a.x; o[1] = a.y; o[2] = a.z; o[3] = a.w;
  o[4] = b.x; o[5] = b.y; o[6] = b.z; o[7] = b.w;
}

// ---------------------------------------------------------------- GEMM
// C[M,128] = A[M,K] @ B[K,128] (+bias, optional relu, optional per-row scale)
template <int K>
__global__ __launch_bounds__(256)
void k_gemm(const float* __restrict__ A, const float* __restrict__ B,
            const float* __restrict__ bias, const float* __restrict__ scale,
            float* __restrict__ C, const int do_relu) {
  __shared__ float As[64][33];
  const int tid = threadIdx.x;
  const int tx = tid & 15;
  const int ty = tid >> 4;
  const int m0 = blockIdx.x * 64;

  float acc[4][8];
#pragma unroll
  for (int i = 0; i < 4; ++i)
#pragma unroll
    for (int j = 0; j < 8; ++j) acc[i][j] = 0.f;

  const int rs = tid >> 2;
  const int ks = (tid & 3) * 8;

  for (int k0 = 0; k0 < K; k0 += 32) {
    float av8[8];
    const int gm = m0 + rs;
    if (gm < N_NODES) {
      load8(&A[(size_t)gm * K + k0 + ks], av8);
    } else {
#pragma unroll
      for (int j = 0; j < 8; ++j) av8[j] = 0.f;
    }
    __syncthreads();
#pragma unroll
    for (int j = 0; j < 8; ++j) As[rs][ks + j] = av8[j];
    __syncthreads();

    const float* Bp = B + (size_t)k0 * DIM_H + tx * 8;
#pragma unroll 4
    for (int k = 0; k < 32; ++k) {
      float bv[8];
      load8(Bp + (size_t)k * DIM_H, bv);
      float av[4];
#pragma unroll
      for (int rr = 0; rr < 4; ++rr) av[rr] = As[ty * 4 + rr][k];
#pragma unroll
      for (int rr = 0; rr < 4; ++rr)
#pragma unroll
        for (int cc = 0; cc < 8; ++cc)
          acc[rr][cc] = fmaf(av[rr], bv[cc], acc[rr][cc]);
    }
  }

  float bs[8];
  if (bias) {
    load8(bias + tx * 8, bs);
  } else {
#pragma unroll
    for (int j = 0; j < 8; ++j) bs[j] = 0.f;
  }
#pragma unroll
  for (int rr = 0; rr < 4; ++rr) {
    const int gm = m0 + ty * 4 + rr;
    if (gm < N_NODES) {
      float sc = scale ? scale[gm] : 1.0f;
      float v[8];
#pragma unroll
      for (int cc = 0; cc < 8; ++cc) {
        float t = acc[rr][cc] + bs[cc];
        if (do_relu) t = fmaxf(t, 0.f);
        v[cc] = t * sc;
      }
      float* Cp = &C[(size_t)gm * DIM_H + tx * 8];
      reinterpret_cast<float4*>(Cp)[0] = make_float4(v[0], v[1], v[2], v[3]);
      reinterpret_cast<float4*>(Cp)[1] = make_float4(v[4], v[5], v[6], v[7]);
    }
  }
}

// ---------------------------------------------------------------- CSR gather
// t is prescaled by dinv[row]. h[i] = bias + dinv[i]*(t[i] + sum_{s in in(i)} t[s])
// off[] holds ENDS (post-fill); start(i) = (i==0) ? 0 : off[i-1].
// one wave per node, float2 per lane.
__global__ __launch_bounds__(256)
void k_aggr_csr(const int* __restrict__ off, const int* __restrict__ csr,
                const float* __restrict__ t, const float* __restrict__ dinv,
                const float* __restrict__ bias, float* __restrict__ h) {
  int node = blockIdx.x * 4 + (threadIdx.x >> 6);
  if (node >= N_NODES) return;
  int lane = threadIdx.x & 63;
  const float2* t2 = (const float2*)t;
  int start = (node == 0) ? 0 : off[node - 1];
  int end = off[node];
  float2 acc = t2[(size_t)node * 64 + lane];  // self term (prescaled)
  int e = start;
  for (; e + 1 < end; e += 2) {
    int s0 = csr[e], s1 = csr[e + 1];
    float2 v0 = t2[(size_t)s0 * 64 + lane];
    float2 v1 = t2[(size_t)s1 * 64 + lane];
    acc.x += v0.x + v1.x;
    acc.y += v0.y + v1.y;
  }
  if (e < end) {
    int s0 = csr[e];
    float2 v0 = t2[(size_t)s0 * 64 + lane];
    acc.x += v0.x;
    acc.y += v0.y;
  }
  float dn = dinv[node];
  float2 b = ((const float2*)bias)[lane];
  float2 o;
  o.x = b.x + dn * acc.x;
  o.y = b.y + dn * acc.y;
  ((float2*)h)[(size_t)node * 64 + lane] = o;
}

// ------------------------------------------- fallback atomic aggregation
__global__ __launch_bounds__(256)
void k_aggr_init(const float* __restrict__ t, const float* __restrict__ dinv,
                 const float* __restrict__ bias, float* __restrict__ h) {
  int idx = blockIdx.x * 256 + threadIdx.x;
  if (idx < N_NODES * DIM_H) {
    int i = idx >> 7;
    int c = idx & 127;
    float d = dinv[i];
    h[idx] = bias[c] + t[idx] * d * d;
  }
}

__global__ __launch_bounds__(256)
void k_aggr_edges(const int* __restrict__ eidx, const int* __restrict__ flag,
                  const float* __restrict__ t, const float* __restrict__ dinv,
                  float* __restrict__ h) {
  int e = blockIdx.x * 2 + (threadIdx.x >> 7);
  int c = threadIdx.x & 127;
  int is64 = *flag;
  if (e < N_EDGES) {
    unsigned s = (unsigned)get_src(eidx, is64, e);
    unsigned d = (unsigned)get_dst(eidx, is64, e);
    if (s < N_NODES && d < N_NODES) {
      float nrm = dinv[s] * dinv[d];
      unsafeAtomicAdd(&h[(size_t)d * DIM_H + c], t[(size_t)s * DIM_H + c] * nrm);
    }
  }
}

// ---------------------------------------------------------------- head
__global__ __launch_bounds__(256)
void k_head(const float* __restrict__ h, const float* __restrict__ Wh,
            const float* __restrict__ bh, float* __restrict__ out) {
  int node = blockIdx.x * 4 + (threadIdx.x >> 6);
  int lane = threadIdx.x & 63;
  if (node >= N_NODES) return;
  float h0 = h[(size_t)node * DIM_H + lane];
  float h1 = h[(size_t)node * DIM_H + 64 + lane];
  float s0 = h0 * Wh[lane * 2 + 0] + h1 * Wh[(lane + 64) * 2 + 0];
  float s1 = h0 * Wh[lane * 2 + 1] + h1 * Wh[(lane + 64) * 2 + 1];
#pragma unroll
  for (int off = 32; off > 0; off >>= 1) {
    s0 += __shfl_down(s0, off);
    s1 += __shfl_down(s1, off);
  }
  if (lane == 0) {
    reinterpret_cast<float2*>(out)[node] = make_float2(s0 + bh[0], s1 + bh[1]);
  }
}

// ---------------------------------------------------------------- launch
extern "C" void kernel_launch(void* const* d_in, const int* in_sizes, int n_in,
                              void* d_out, int out_size, void* d_ws, size_t ws_size,
                              hipStream_t stream) {
  (void)in_sizes; (void)n_in; (void)out_size;
  const int* eidx = (const int*)d_in[0];
  const float* x  = (const float*)d_in[1];
  const float* Wi = (const float*)d_in[2];
  const float* bi = (const float*)d_in[3];
  const float* W1 = (const float*)d_in[4];
  const float* b1 = (const float*)d_in[5];
  const float* W2 = (const float*)d_in[6];
  const float* b2 = (const float*)d_in[7];
  const float* Wh = (const float*)d_in[8];
  const float* bh = (const float*)d_in[9];
  float* out = (float*)d_out;

  // CSR layout (~109.7 MB):
  //   flag @ 0            off @ 4096 (N ints)       dinv @ 404480 (N f32)
  //   csr  @ 804864 (E ints)   bufA @ 7205376 (N*128 f32)   bufB @ 58405888
  char* ws = (char*)d_ws;
  int*   flag = (int*)ws;
  int*   off  = (int*)(ws + 4096);
  float* dinv = (float*)(ws + 404480);
  int*   csr  = (int*)(ws + 804864);
  float* bufA = (float*)(ws + 7205376);
  float* bufB = (float*)(ws + 58405888);
  const size_t needed_csr = 58405888 + (size_t)N_NODES * DIM_H * 4;  // ~109.6 MB

  const int gN  = (N_NODES + 255) / 256;
  const int gE  = (N_EDGES + 255) / 256;
  const int gM  = (N_NODES + 63) / 64;
  const int gW  = (N_NODES + 3) / 4;   // wave-per-node kernels

  k_detect<<<1, 1024, 0, stream>>>(eidx, flag);

  if (ws_size >= needed_csr) {
    // ---- CSR path ----
    k_zero<<<gN, 256, 0, stream>>>(off, N_NODES);
    k_count<<<gE, 256, 0, stream>>>(eidx, flag, off);
    k_dinv<<<gN, 256, 0, stream>>>(off, dinv);
    k_scan<<<1, 1024, 0, stream>>>(off);
    k_fill<<<gE, 256, 0, stream>>>(eidx, flag, off, csr);

    // h1 = relu(x @ Wi + bi)
    k_gemm<DIM_IN><<<gM, 256, 0, stream>>>(x, Wi, bi, nullptr, bufA, 1);
    // layer 1: t = (h1 @ W1) * dinv ; h2 = bias + dinv*(self + gather)
    k_gemm<DIM_H><<<gM, 256, 0, stream>>>(bufA, W1, nullptr, dinv, bufB, 0);
    k_aggr_csr<<<gW, 256, 0, stream>>>(off, csr, bufB, dinv, b1, bufA);
    // layer 2
    k_gemm<DIM_H><<<gM, 256, 0, stream>>>(bufA, W2, nullptr, dinv, bufB, 0);
    k_aggr_csr<<<gW, 256, 0, stream>>>(off, csr, bufB, dinv, b2, bufA);
  } else {
    // ---- fallback: atomic scatter (round-3 structure) ----
    float* fbA = (float*)(ws + 804864);
    float* fbB = (float*)(ws + 804864 + (size_t)N_NODES * DIM_H * 4);
    const int gNH = (N_NODES * DIM_H + 255) / 256;
    const int gE2 = (N_EDGES + 1) / 2;
    k_zero<<<gN, 256, 0, stream>>>(off, N_NODES);
    k_count<<<gE, 256, 0, stream>>>(eidx, flag, off);
    k_dinv<<<gN, 256, 0, stream>>>(off, dinv);

    k_gemm<DIM_IN><<<gM, 256, 0, stream>>>(x, Wi, bi, nullptr, fbA, 1);
    k_gemm<DIM_H><<<gM, 256, 0, stream>>>(fbA, W1, nullptr, nullptr, fbB, 0);
    k_aggr_init<<<gNH, 256, 0, stream>>>(fbB, dinv, b1, fbA);
    k_aggr_edges<<<gE2, 256, 0, stream>>>(eidx, flag, fbB, dinv, fbA);
    k_gemm<DIM_H><<<gM, 256, 0, stream>>>(fbA, W2, nullptr, nullptr, fbB, 0);
    k_aggr_init<<<gNH, 256, 0, stream>>>(fbB, dinv, b2, fbA);
    k_aggr_edges<<<gE2, 256, 0, stream>>>(eidx, flag, fbB, dinv, fbA);
    k_head<<<gW, 256, 0, stream>>>(fbA, Wh, bh, out);
    return;
  }

  k_head<<<gW, 256, 0, stream>>>(bufA, Wh, bh, out);
}

// Round 5
// 871.898 us; speedup vs baseline: 2.2788x; 1.2245x over previous
//
#include <hip/hip_runtime.h>
#include <hip/hip_bf16.h>

#define N_NODES 100000
#define N_EDGES 1600000
#define DIM_IN  256
#define DIM_H   128

typedef __attribute__((ext_vector_type(8))) short short8;
typedef __attribute__((ext_vector_type(4))) float f32x4;

// ------------------------------------------------- edge_index width detect
__global__ __launch_bounds__(1024) void k_detect(const int* __restrict__ e,
                                                 int* __restrict__ flag) {
  __shared__ int s;
  if (threadIdx.x == 0) s = 0;
  __syncthreads();
  atomicOr(&s, e[2 * threadIdx.x + 1]);
  __syncthreads();
  if (threadIdx.x == 0) *flag = (s == 0) ? 1 : 0;
}

__device__ __forceinline__ int get_src(const int* e, int is64, int i) {
  return is64 ? e[2 * i] : e[i];
}
__device__ __forceinline__ int get_dst(const int* e, int is64, int i) {
  return is64 ? e[2 * (N_EDGES + i)] : e[N_EDGES + i];
}

// ---------------------------------------------------------------- degree/CSR
__global__ __launch_bounds__(256) void k_zero(int* __restrict__ p, int n) {
  int i = blockIdx.x * 256 + threadIdx.x;
  if (i < n) p[i] = 0;
}

__global__ __launch_bounds__(256) void k_count(const int* __restrict__ eidx,
                                               const int* __restrict__ flag,
                                               int* __restrict__ off) {
  int e = blockIdx.x * 256 + threadIdx.x;
  int is64 = *flag;
  if (e < N_EDGES) {
    unsigned d = (unsigned)get_dst(eidx, is64, e);
    if (d < N_NODES) atomicAdd(&off[d], 1);
  }
}

__global__ __launch_bounds__(256) void k_dinv(const int* __restrict__ off,
                                              float* __restrict__ dinv) {
  int i = blockIdx.x * 256 + threadIdx.x;
  if (i < N_NODES) dinv[i] = rsqrtf(1.0f + (float)off[i]);
}

__global__ __launch_bounds__(1024) void k_scan(int* __restrict__ off) {
  __shared__ int part[1024];
  const int C = (N_NODES + 1023) / 1024;
  int t = threadIdx.x;
  int lo = t * C, hi = min(lo + C, N_NODES);
  int s = 0;
  for (int i = lo; i < hi; ++i) s += off[i];
  part[t] = s;
  __syncthreads();
  for (int d = 1; d < 1024; d <<= 1) {
    int v = (t >= d) ? part[t - d] : 0;
    __syncthreads();
    part[t] += v;
    __syncthreads();
  }
  int base = (t == 0) ? 0 : part[t - 1];
  for (int i = lo; i < hi; ++i) {
    int c = off[i];
    off[i] = base;
    base += c;
  }
}

__global__ __launch_bounds__(256) void k_fill(const int* __restrict__ eidx,
                                              const int* __restrict__ flag,
                                              int* __restrict__ off,
                                              int* __restrict__ csr) {
  int e = blockIdx.x * 256 + threadIdx.x;
  int is64 = *flag;
  if (e < N_EDGES) {
    unsigned s = (unsigned)get_src(eidx, is64, e);
    unsigned d = (unsigned)get_dst(eidx, is64, e);
    if (s < N_NODES && d < N_NODES) {
      int pos = atomicAdd(&off[d], 1);
      csr[pos] = (int)s;
    }
  }
}

// ---------------------------------------------------------------- bf16 split
__device__ __forceinline__ ushort f2bf(float f) {
  unsigned u = __float_as_uint(f);
  unsigned r = (u + 0x7fffu + ((u >> 16) & 1u)) >> 16;
  return (ushort)r;
}
__device__ __forceinline__ float bf2f(ushort h) {
  return __uint_as_float(((unsigned)h) << 16);
}

__device__ __forceinline__ void load8(const float* p, float* o) {
  float4 a = reinterpret_cast<const float4*>(p)[0];
  float4 b = reinterpret_cast<const float4*>(p)[1];
  o[0] = a.x; o[1] = a.y; o[2] = a.z; o[3] = a.w;
  o[4] = b.x; o[5] = b.y; o[6] = b.z; o[7] = b.w;
}

// Split weight W[K x 128] into MFMA B-fragment planes.
// entry idx = ((c*8 + nt)*4 + q)*16 + n  holds B[k=c*32+q*8+j][nt*16+n], j=0..7
// hi plane at outHi[idx], lo plane at outHi + CH*512 entries.
__global__ __launch_bounds__(256)
void k_bsplit(const float* __restrict__ W, const int CH, ushort* __restrict__ outHi) {
  int idx = blockIdx.x * 256 + threadIdx.x;
  if (idx >= CH * 512) return;
  int n  = idx & 15;
  int qq = (idx >> 4) & 3;
  int nt = (idx >> 6) & 7;
  int c  = idx >> 9;
  int col = nt * 16 + n;
  short8 h8, l8;
#pragma unroll
  for (int j = 0; j < 8; ++j) {
    float v = W[(size_t)(c * 32 + qq * 8 + j) * DIM_H + col];
    ushort hb = f2bf(v);
    ushort lb = f2bf(v - bf2f(hb));
    h8[j] = (short)hb;
    l8[j] = (short)lb;
  }
  ((short8*)outHi)[idx] = h8;
  ((short8*)outHi)[CH * 512 + idx] = l8;
}

// ---------------------------------------------------------------- MFMA GEMM
// C[M,128] = A[M,K] @ B[K,128], bf16x2 split (hi*hi + hi*lo + lo*hi), fp32 acc.
// Block: 256 threads = 4 waves, tile M=64, N=128; wave w covers cols w*32..+32.
template <int K>
__global__ __launch_bounds__(256)
void k_gemm_mfma(const float* __restrict__ A, const ushort* __restrict__ Bfrag,
                 const float* __restrict__ bias, const float* __restrict__ scale,
                 float* __restrict__ C, const int do_relu) {
  constexpr int CH = K / 32;
  __shared__ __align__(16) ushort AhiS[256 * 8];  // entry = mt*64 + q*16 + m
  __shared__ __align__(16) ushort AloS[256 * 8];
  const int tid = threadIdx.x;
  const int m0 = blockIdx.x * 64;
  const int wave = tid >> 6, lane = tid & 63;
  const int m_l = lane & 15, quad = lane >> 4;
  const int rs = tid >> 2, q = tid & 3;  // staging: row, k-quad

  f32x4 acc[2][4];
#pragma unroll
  for (int i = 0; i < 2; ++i)
#pragma unroll
    for (int j = 0; j < 4; ++j) acc[i][j] = (f32x4){0.f, 0.f, 0.f, 0.f};

  const short8* Bhi8 = (const short8*)Bfrag;
  const short8* Blo8 = Bhi8 + CH * 512;
  short8* Ah8 = (short8*)AhiS;
  short8* Al8 = (short8*)AloS;

  for (int c = 0; c < CH; ++c) {
    // ---- stage A chunk (64 rows x 32 k) as split fragment entries ----
    float v[8];
    const int gm = m0 + rs;
    if (gm < N_NODES) {
      load8(&A[(size_t)gm * K + c * 32 + q * 8], v);
    } else {
#pragma unroll
      for (int j = 0; j < 8; ++j) v[j] = 0.f;
    }
    short8 h8, l8;
#pragma unroll
    for (int j = 0; j < 8; ++j) {
      ushort hb = f2bf(v[j]);
      ushort lb = f2bf(v[j] - bf2f(hb));
      h8[j] = (short)hb;
      l8[j] = (short)lb;
    }
    __syncthreads();
    const int ent = (rs >> 4) * 64 + q * 16 + (rs & 15);
    Ah8[ent] = h8;
    Al8[ent] = l8;
    __syncthreads();

    // ---- fragments + MFMA ----
    short8 ahi[4], alo[4];
#pragma unroll
    for (int mt = 0; mt < 4; ++mt) {
      ahi[mt] = Ah8[mt * 64 + quad * 16 + m_l];
      alo[mt] = Al8[mt * 64 + quad * 16 + m_l];
    }
#pragma unroll
    for (int ntl = 0; ntl < 2; ++ntl) {
      const int bent = ((c * 8 + wave * 2 + ntl) * 4 + quad) * 16 + m_l;
      short8 bhi = Bhi8[bent];
      short8 blo = Blo8[bent];
#pragma unroll
      for (int mt = 0; mt < 4; ++mt) {
        acc[ntl][mt] = __builtin_amdgcn_mfma_f32_16x16x32_bf16(ahi[mt], bhi, acc[ntl][mt], 0, 0, 0);
        acc[ntl][mt] = __builtin_amdgcn_mfma_f32_16x16x32_bf16(ahi[mt], blo, acc[ntl][mt], 0, 0, 0);
        acc[ntl][mt] = __builtin_amdgcn_mfma_f32_16x16x32_bf16(alo[mt], bhi, acc[ntl][mt], 0, 0, 0);
      }
    }
  }

  // ---- epilogue: C/D layout col = lane&15, row = quad*4 + r ----
#pragma unroll
  for (int ntl = 0; ntl < 2; ++ntl) {
    const int colg = (wave * 2 + ntl) * 16 + m_l;
    const float bv = bias ? bias[colg] : 0.f;
#pragma unroll
    for (int mt = 0; mt < 4; ++mt) {
#pragma unroll
      for (int r = 0; r < 4; ++r) {
        const int rowg = m0 + mt * 16 + quad * 4 + r;
        if (rowg < N_NODES) {
          float t = acc[ntl][mt][r] + bv;
          if (do_relu) t = fmaxf(t, 0.f);
          const float sc = scale ? scale[rowg] : 1.0f;
          C[(size_t)rowg * DIM_H + colg] = t * sc;
        }
      }
    }
  }
}

// ---------------------------------------------------------------- fp32 GEMM (fallback tiers)
template <int K>
__global__ __launch_bounds__(256)
void k_gemm(const float* __restrict__ A, const float* __restrict__ B,
            const float* __restrict__ bias, const float* __restrict__ scale,
            float* __restrict__ C, const int do_relu) {
  __shared__ float As[64][33];
  const int tid = threadIdx.x;
  const int tx = tid & 15;
  const int ty = tid >> 4;
  const int m0 = blockIdx.x * 64;

  float acc[4][8];
#pragma unroll
  for (int i = 0; i < 4; ++i)
#pragma unroll
    for (int j = 0; j < 8; ++j) acc[i][j] = 0.f;

  const int rs = tid >> 2;
  const int ks = (tid & 3) * 8;

  for (int k0 = 0; k0 < K; k0 += 32) {
    float av8[8];
    const int gm = m0 + rs;
    if (gm < N_NODES) {
      load8(&A[(size_t)gm * K + k0 + ks], av8);
    } else {
#pragma unroll
      for (int j = 0; j < 8; ++j) av8[j] = 0.f;
    }
    __syncthreads();
#pragma unroll
    for (int j = 0; j < 8; ++j) As[rs][ks + j] = av8[j];
    __syncthreads();

    const float* Bp = B + (size_t)k0 * DIM_H + tx * 8;
#pragma unroll 4
    for (int k = 0; k < 32; ++k) {
      float bv[8];
      load8(Bp + (size_t)k * DIM_H, bv);
      float av[4];
#pragma unroll
      for (int rr = 0; rr < 4; ++rr) av[rr] = As[ty * 4 + rr][k];
#pragma unroll
      for (int rr = 0; rr < 4; ++rr)
#pragma unroll
        for (int cc = 0; cc < 8; ++cc)
          acc[rr][cc] = fmaf(av[rr], bv[cc], acc[rr][cc]);
    }
  }

  float bs[8];
  if (bias) {
    load8(bias + tx * 8, bs);
  } else {
#pragma unroll
    for (int j = 0; j < 8; ++j) bs[j] = 0.f;
  }
#pragma unroll
  for (int rr = 0; rr < 4; ++rr) {
    const int gm = m0 + ty * 4 + rr;
    if (gm < N_NODES) {
      float sc = scale ? scale[gm] : 1.0f;
      float v[8];
#pragma unroll
      for (int cc = 0; cc < 8; ++cc) {
        float t = acc[rr][cc] + bs[cc];
        if (do_relu) t = fmaxf(t, 0.f);
        v[cc] = t * sc;
      }
      float* Cp = &C[(size_t)gm * DIM_H + tx * 8];
      reinterpret_cast<float4*>(Cp)[0] = make_float4(v[0], v[1], v[2], v[3]);
      reinterpret_cast<float4*>(Cp)[1] = make_float4(v[4], v[5], v[6], v[7]);
    }
  }
}

// ---------------------------------------------------------------- CSR gather
__global__ __launch_bounds__(256)
void k_aggr_csr(const int* __restrict__ off, const int* __restrict__ csr,
                const float* __restrict__ t, const float* __restrict__ dinv,
                const float* __restrict__ bias, float* __restrict__ h) {
  int node = blockIdx.x * 4 + (threadIdx.x >> 6);
  if (node >= N_NODES) return;
  int lane = threadIdx.x & 63;
  const float2* t2 = (const float2*)t;
  int start = (node == 0) ? 0 : off[node - 1];
  int end = off[node];
  float2 acc = t2[(size_t)node * 64 + lane];  // self term (prescaled)
  int e = start;
  for (; e + 1 < end; e += 2) {
    int s0 = csr[e], s1 = csr[e + 1];
    float2 v0 = t2[(size_t)s0 * 64 + lane];
    float2 v1 = t2[(size_t)s1 * 64 + lane];
    acc.x += v0.x + v1.x;
    acc.y += v0.y + v1.y;
  }
  if (e < end) {
    int s0 = csr[e];
    float2 v0 = t2[(size_t)s0 * 64 + lane];
    acc.x += v0.x;
    acc.y += v0.y;
  }
  float dn = dinv[node];
  float2 b = ((const float2*)bias)[lane];
  float2 o;
  o.x = b.x + dn * acc.x;
  o.y = b.y + dn * acc.y;
  ((float2*)h)[(size_t)node * 64 + lane] = o;
}

// ------------------------------------------- fallback atomic aggregation
__global__ __launch_bounds__(256)
void k_aggr_init(const float* __restrict__ t, const float* __restrict__ dinv,
                 const float* __restrict__ bias, float* __restrict__ h) {
  int idx = blockIdx.x * 256 + threadIdx.x;
  if (idx < N_NODES * DIM_H) {
    int i = idx >> 7;
    int c = idx & 127;
    float d = dinv[i];
    h[idx] = bias[c] + t[idx] * d * d;
  }
}

__global__ __launch_bounds__(256)
void k_aggr_edges(const int* __restrict__ eidx, const int* __restrict__ flag,
                  const float* __restrict__ t, const float* __restrict__ dinv,
                  float* __restrict__ h) {
  int e = blockIdx.x * 2 + (threadIdx.x >> 7);
  int c = threadIdx.x & 127;
  int is64 = *flag;
  if (e < N_EDGES) {
    unsigned s = (unsigned)get_src(eidx, is64, e);
    unsigned d = (unsigned)get_dst(eidx, is64, e);
    if (s < N_NODES && d < N_NODES) {
      float nrm = dinv[s] * dinv[d];
      unsafeAtomicAdd(&h[(size_t)d * DIM_H + c], t[(size_t)s * DIM_H + c] * nrm);
    }
  }
}

// ---------------------------------------------------------------- head
__global__ __launch_bounds__(256)
void k_head(const float* __restrict__ h, const float* __restrict__ Wh,
            const float* __restrict__ bh, float* __restrict__ out) {
  int node = blockIdx.x * 4 + (threadIdx.x >> 6);
  int lane = threadIdx.x & 63;
  if (node >= N_NODES) return;
  float h0 = h[(size_t)node * DIM_H + lane];
  float h1 = h[(size_t)node * DIM_H + 64 + lane];
  float s0 = h0 * Wh[lane * 2 + 0] + h1 * Wh[(lane + 64) * 2 + 0];
  float s1 = h0 * Wh[lane * 2 + 1] + h1 * Wh[(lane + 64) * 2 + 1];
#pragma unroll
  for (int off = 32; off > 0; off >>= 1) {
    s0 += __shfl_down(s0, off);
    s1 += __shfl_down(s1, off);
  }
  if (lane == 0) {
    reinterpret_cast<float2*>(out)[node] = make_float2(s0 + bh[0], s1 + bh[1]);
  }
}

// ---------------------------------------------------------------- launch
extern "C" void kernel_launch(void* const* d_in, const int* in_sizes, int n_in,
                              void* d_out, int out_size, void* d_ws, size_t ws_size,
                              hipStream_t stream) {
  (void)in_sizes; (void)n_in; (void)out_size;
  const int* eidx = (const int*)d_in[0];
  const float* x  = (const float*)d_in[1];
  const float* Wi = (const float*)d_in[2];
  const float* bi = (const float*)d_in[3];
  const float* W1 = (const float*)d_in[4];
  const float* b1 = (const float*)d_in[5];
  const float* W2 = (const float*)d_in[6];
  const float* b2 = (const float*)d_in[7];
  const float* Wh = (const float*)d_in[8];
  const float* bh = (const float*)d_in[9];
  float* out = (float*)d_out;

  const int gN  = (N_NODES + 255) / 256;
  const int gE  = (N_EDGES + 255) / 256;
  const int gM  = (N_NODES + 63) / 64;
  const int gW  = (N_NODES + 3) / 4;

  char* ws = (char*)d_ws;
  int* flag = (int*)ws;
  k_detect<<<1, 1024, 0, stream>>>(eidx, flag);

  // ---- tier 1: MFMA + CSR (needs ~109.87 MB) ----
  // flag@0 | bfWi@4096(128K) | bfW1@135168(64K) | bfW2@200704(64K) |
  // off@266240 | dinv@666240 | csr@1066240 | bufA@7466496 | bufB@58666496
  const size_t need1 = 109866496;
  // ---- tier 2: fp32 GEMM + CSR (round-4 layout, needs ~109.6 MB) ----
  const size_t need2 = 58405888 + (size_t)N_NODES * DIM_H * 4;

  if (ws_size >= need1) {
    ushort* bfWi = (ushort*)(ws + 4096);
    ushort* bfW1 = (ushort*)(ws + 135168);
    ushort* bfW2 = (ushort*)(ws + 200704);
    int*    off  = (int*)(ws + 266240);
    float*  dinv = (float*)(ws + 666240);
    int*    csr  = (int*)(ws + 1066240);
    float*  bufA = (float*)(ws + 7466496);
    float*  bufB = (float*)(ws + 58666496);

    // weight fragment split (Wi: CH=8, W1/W2: CH=4)
    k_bsplit<<<16, 256, 0, stream>>>(Wi, 8, bfWi);
    k_bsplit<<<8, 256, 0, stream>>>(W1, 4, bfW1);
    k_bsplit<<<8, 256, 0, stream>>>(W2, 4, bfW2);

    // CSR build + dinv
    k_zero<<<gN, 256, 0, stream>>>(off, N_NODES);
    k_count<<<gE, 256, 0, stream>>>(eidx, flag, off);
    k_dinv<<<gN, 256, 0, stream>>>(off, dinv);
    k_scan<<<1, 1024, 0, stream>>>(off);
    k_fill<<<gE, 256, 0, stream>>>(eidx, flag, off, csr);

    // h1 = relu(x @ Wi + bi)
    k_gemm_mfma<DIM_IN><<<gM, 256, 0, stream>>>(x, bfWi, bi, nullptr, bufA, 1);
    // layer 1: t = (h1 @ W1) * dinv ; h2 = b1 + dinv*(self + gather)
    k_gemm_mfma<DIM_H><<<gM, 256, 0, stream>>>(bufA, bfW1, nullptr, dinv, bufB, 0);
    k_aggr_csr<<<gW, 256, 0, stream>>>(off, csr, bufB, dinv, b1, bufA);
    // layer 2
    k_gemm_mfma<DIM_H><<<gM, 256, 0, stream>>>(bufA, bfW2, nullptr, dinv, bufB, 0);
    k_aggr_csr<<<gW, 256, 0, stream>>>(off, csr, bufB, dinv, b2, bufA);

    k_head<<<gW, 256, 0, stream>>>(bufA, Wh, bh, out);
  } else if (ws_size >= need2) {
    int*   off  = (int*)(ws + 4096);
    float* dinv = (float*)(ws + 404480);
    int*   csr  = (int*)(ws + 804864);
    float* bufA = (float*)(ws + 7205376);
    float* bufB = (float*)(ws + 58405888);

    k_zero<<<gN, 256, 0, stream>>>(off, N_NODES);
    k_count<<<gE, 256, 0, stream>>>(eidx, flag, off);
    k_dinv<<<gN, 256, 0, stream>>>(off, dinv);
    k_scan<<<1, 1024, 0, stream>>>(off);
    k_fill<<<gE, 256, 0, stream>>>(eidx, flag, off, csr);

    k_gemm<DIM_IN><<<gM, 256, 0, stream>>>(x, Wi, bi, nullptr, bufA, 1);
    k_gemm<DIM_H><<<gM, 256, 0, stream>>>(bufA, W1, nullptr, dinv, bufB, 0);
    k_aggr_csr<<<gW, 256, 0, stream>>>(off, csr, bufB, dinv, b1, bufA);
    k_gemm<DIM_H><<<gM, 256, 0, stream>>>(bufA, W2, nullptr, dinv, bufB, 0);
    k_aggr_csr<<<gW, 256, 0, stream>>>(off, csr, bufB, dinv, b2, bufA);
    k_head<<<gW, 256, 0, stream>>>(bufA, Wh, bh, out);
  } else {
    int*   off  = (int*)(ws + 4096);
    float* dinv = (float*)(ws + 404480);
    float* fbA  = (float*)(ws + 804864);
    float* fbB  = (float*)(ws + 804864 + (size_t)N_NODES * DIM_H * 4);
    const int gNH = (N_NODES * DIM_H + 255) / 256;
    const int gE2 = (N_EDGES + 1) / 2;
    k_zero<<<gN, 256, 0, stream>>>(off, N_NODES);
    k_count<<<gE, 256, 0, stream>>>(eidx, flag, off);
    k_dinv<<<gN, 256, 0, stream>>>(off, dinv);

    k_gemm<DIM_IN><<<gM, 256, 0, stream>>>(x, Wi, bi, nullptr, fbA, 1);
    k_gemm<DIM_H><<<gM, 256, 0, stream>>>(fbA, W1, nullptr, nullptr, fbB, 0);
    k_aggr_init<<<gNH, 256, 0, stream>>>(fbB, dinv, b1, fbA);
    k_aggr_edges<<<gE2, 256, 0, stream>>>(eidx, flag, fbB, dinv, fbA);
    k_gemm<DIM_H><<<gM, 256, 0, stream>>>(fbA, W2, nullptr, nullptr, fbB, 0);
    k_aggr_init<<<gNH, 256, 0, stream>>>(fbB, dinv, b2, fbA);
    k_aggr_edges<<<gE2, 256, 0, stream>>>(eidx, flag, fbB, dinv, fbA);
    k_head<<<gW, 256, 0, stream>>>(fbA, Wh, bh, out);
  }
}

// Round 6
// 719.573 us; speedup vs baseline: 2.7612x; 1.2117x over previous
//
#include <hip/hip_runtime.h>
#include <hip/hip_bf16.h>

#define N_NODES 100000
#define N_EDGES 1600000
#define DIM_IN  256
#define DIM_H   128

#define SCAN_B 512
#define SCAN_NB ((N_NODES + SCAN_B - 1) / SCAN_B)   // 196

typedef __attribute__((ext_vector_type(8))) short short8;
typedef __attribute__((ext_vector_type(4))) float f32x4;

// ------------------------------------------------- edge_index width detect
__global__ __launch_bounds__(1024) void k_detect(const int* __restrict__ e,
                                                 int* __restrict__ flag) {
  __shared__ int s;
  if (threadIdx.x == 0) s = 0;
  __syncthreads();
  atomicOr(&s, e[2 * threadIdx.x + 1]);
  __syncthreads();
  if (threadIdx.x == 0) *flag = (s == 0) ? 1 : 0;
}

__device__ __forceinline__ int get_src(const int* e, int is64, int i) {
  return is64 ? e[2 * i] : e[i];
}
__device__ __forceinline__ int get_dst(const int* e, int is64, int i) {
  return is64 ? e[2 * (N_EDGES + i)] : e[N_EDGES + i];
}

// ---------------------------------------------------------------- degree/CSR
__global__ __launch_bounds__(256) void k_zero(int* __restrict__ p, int n) {
  int i = blockIdx.x * 256 + threadIdx.x;
  if (i < n) p[i] = 0;
}

__global__ __launch_bounds__(256) void k_count(const int* __restrict__ eidx,
                                               const int* __restrict__ flag,
                                               int* __restrict__ off) {
  int e = blockIdx.x * 256 + threadIdx.x;
  int is64 = *flag;
  if (e < N_EDGES) {
    unsigned d = (unsigned)get_dst(eidx, is64, e);
    if (d < N_NODES) atomicAdd(&off[d], 1);
  }
}

__global__ __launch_bounds__(256) void k_dinv(const int* __restrict__ off,
                                              float* __restrict__ dinv) {
  int i = blockIdx.x * 256 + threadIdx.x;
  if (i < N_NODES) dinv[i] = rsqrtf(1.0f + (float)off[i]);
}

// ---- 3-phase parallel exclusive scan of off[0..N_NODES) ----
__global__ __launch_bounds__(SCAN_B)
void k_scan1(int* __restrict__ off, int* __restrict__ bsum) {
  __shared__ int s[SCAN_B];
  int t = threadIdx.x;
  int i = blockIdx.x * SCAN_B + t;
  int v = (i < N_NODES) ? off[i] : 0;
  s[t] = v;
  __syncthreads();
  for (int d = 1; d < SCAN_B; d <<= 1) {
    int u = (t >= d) ? s[t - d] : 0;
    __syncthreads();
    s[t] += u;
    __syncthreads();
  }
  if (i < N_NODES) off[i] = s[t] - v;  // exclusive
  if (t == SCAN_B - 1) bsum[blockIdx.x] = s[t];
}

__global__ __launch_bounds__(256)
void k_scan2(int* __restrict__ bsum) {
  __shared__ int s[256];
  int t = threadIdx.x;
  int v = (t < SCAN_NB) ? bsum[t] : 0;
  s[t] = v;
  __syncthreads();
  for (int d = 1; d < 256; d <<= 1) {
    int u = (t >= d) ? s[t - d] : 0;
    __syncthreads();
    s[t] += u;
    __syncthreads();
  }
  if (t < SCAN_NB) bsum[t] = s[t] - v;  // exclusive block offsets
}

__global__ __launch_bounds__(SCAN_B)
void k_scan3(int* __restrict__ off, const int* __restrict__ bsum) {
  int i = blockIdx.x * SCAN_B + threadIdx.x;
  if (i < N_NODES) off[i] += bsum[blockIdx.x];
}

__global__ __launch_bounds__(256) void k_fill(const int* __restrict__ eidx,
                                              const int* __restrict__ flag,
                                              int* __restrict__ off,
                                              int* __restrict__ csr) {
  int e = blockIdx.x * 256 + threadIdx.x;
  int is64 = *flag;
  if (e < N_EDGES) {
    unsigned s = (unsigned)get_src(eidx, is64, e);
    unsigned d = (unsigned)get_dst(eidx, is64, e);
    if (s < N_NODES && d < N_NODES) {
      int pos = atomicAdd(&off[d], 1);
      csr[pos] = (int)s;
    }
  }
}

// ---------------------------------------------------------------- bf16 split
__device__ __forceinline__ ushort f2bf(float f) {
  unsigned u = __float_as_uint(f);
  unsigned r = (u + 0x7fffu + ((u >> 16) & 1u)) >> 16;
  return (ushort)r;
}
__device__ __forceinline__ float bf2f(ushort h) {
  return __uint_as_float(((unsigned)h) << 16);
}

__device__ __forceinline__ void load8(const float* p, float* o) {
  float4 a = reinterpret_cast<const float4*>(p)[0];
  float4 b = reinterpret_cast<const float4*>(p)[1];
  o[0] = a.x; o[1] = a.y; o[2] = a.z; o[3] = a.w;
  o[4] = b.x; o[5] = b.y; o[6] = b.z; o[7] = b.w;
}

// Split weight W[K x 128] into MFMA B-fragment planes.
__global__ __launch_bounds__(256)
void k_bsplit(const float* __restrict__ W, const int CH, ushort* __restrict__ outHi) {
  int idx = blockIdx.x * 256 + threadIdx.x;
  if (idx >= CH * 512) return;
  int n  = idx & 15;
  int qq = (idx >> 4) & 3;
  int nt = (idx >> 6) & 7;
  int c  = idx >> 9;
  int col = nt * 16 + n;
  short8 h8, l8;
#pragma unroll
  for (int j = 0; j < 8; ++j) {
    float v = W[(size_t)(c * 32 + qq * 8 + j) * DIM_H + col];
    ushort hb = f2bf(v);
    ushort lb = f2bf(v - bf2f(hb));
    h8[j] = (short)hb;
    l8[j] = (short)lb;
  }
  ((short8*)outHi)[idx] = h8;
  ((short8*)outHi)[CH * 512 + idx] = l8;
}

// ---------------------------------------------------------------- MFMA GEMM
template <int K>
__global__ __launch_bounds__(256)
void k_gemm_mfma(const float* __restrict__ A, const ushort* __restrict__ Bfrag,
                 const float* __restrict__ bias, const float* __restrict__ scale,
                 float* __restrict__ C, const int do_relu) {
  constexpr int CH = K / 32;
  __shared__ __align__(16) ushort AhiS[256 * 8];
  __shared__ __align__(16) ushort AloS[256 * 8];
  const int tid = threadIdx.x;
  const int m0 = blockIdx.x * 64;
  const int wave = tid >> 6, lane = tid & 63;
  const int m_l = lane & 15, quad = lane >> 4;
  const int rs = tid >> 2, q = tid & 3;

  f32x4 acc[2][4];
#pragma unroll
  for (int i = 0; i < 2; ++i)
#pragma unroll
    for (int j = 0; j < 4; ++j) acc[i][j] = (f32x4){0.f, 0.f, 0.f, 0.f};

  const short8* Bhi8 = (const short8*)Bfrag;
  const short8* Blo8 = Bhi8 + CH * 512;
  short8* Ah8 = (short8*)AhiS;
  short8* Al8 = (short8*)AloS;

  for (int c = 0; c < CH; ++c) {
    float v[8];
    const int gm = m0 + rs;
    if (gm < N_NODES) {
      load8(&A[(size_t)gm * K + c * 32 + q * 8], v);
    } else {
#pragma unroll
      for (int j = 0; j < 8; ++j) v[j] = 0.f;
    }
    short8 h8, l8;
#pragma unroll
    for (int j = 0; j < 8; ++j) {
      ushort hb = f2bf(v[j]);
      ushort lb = f2bf(v[j] - bf2f(hb));
      h8[j] = (short)hb;
      l8[j] = (short)lb;
    }
    __syncthreads();
    const int ent = (rs >> 4) * 64 + q * 16 + (rs & 15);
    Ah8[ent] = h8;
    Al8[ent] = l8;
    __syncthreads();

    short8 ahi[4], alo[4];
#pragma unroll
    for (int mt = 0; mt < 4; ++mt) {
      ahi[mt] = Ah8[mt * 64 + quad * 16 + m_l];
      alo[mt] = Al8[mt * 64 + quad * 16 + m_l];
    }
#pragma unroll
    for (int ntl = 0; ntl < 2; ++ntl) {
      const int bent = ((c * 8 + wave * 2 + ntl) * 4 + quad) * 16 + m_l;
      short8 bhi = Bhi8[bent];
      short8 blo = Blo8[bent];
#pragma unroll
      for (int mt = 0; mt < 4; ++mt) {
        acc[ntl][mt] = __builtin_amdgcn_mfma_f32_16x16x32_bf16(ahi[mt], bhi, acc[ntl][mt], 0, 0, 0);
        acc[ntl][mt] = __builtin_amdgcn_mfma_f32_16x16x32_bf16(ahi[mt], blo, acc[ntl][mt], 0, 0, 0);
        acc[ntl][mt] = __builtin_amdgcn_mfma_f32_16x16x32_bf16(alo[mt], bhi, acc[ntl][mt], 0, 0, 0);
      }
    }
  }

#pragma unroll
  for (int ntl = 0; ntl < 2; ++ntl) {
    const int colg = (wave * 2 + ntl) * 16 + m_l;
    const float bv = bias ? bias[colg] : 0.f;
#pragma unroll
    for (int mt = 0; mt < 4; ++mt) {
#pragma unroll
      for (int r = 0; r < 4; ++r) {
        const int rowg = m0 + mt * 16 + quad * 4 + r;
        if (rowg < N_NODES) {
          float t = acc[ntl][mt][r] + bv;
          if (do_relu) t = fmaxf(t, 0.f);
          const float sc = scale ? scale[rowg] : 1.0f;
          C[(size_t)rowg * DIM_H + colg] = t * sc;
        }
      }
    }
  }
}

// ---------------------------------------------------------------- fp32 GEMM (fallback tiers)
template <int K>
__global__ __launch_bounds__(256)
void k_gemm(const float* __restrict__ A, const float* __restrict__ B,
            const float* __restrict__ bias, const float* __restrict__ scale,
            float* __restrict__ C, const int do_relu) {
  __shared__ float As[64][33];
  const int tid = threadIdx.x;
  const int tx = tid & 15;
  const int ty = tid >> 4;
  const int m0 = blockIdx.x * 64;

  float acc[4][8];
#pragma unroll
  for (int i = 0; i < 4; ++i)
#pragma unroll
    for (int j = 0; j < 8; ++j) acc[i][j] = 0.f;

  const int rs = tid >> 2;
  const int ks = (tid & 3) * 8;

  for (int k0 = 0; k0 < K; k0 += 32) {
    float av8[8];
    const int gm = m0 + rs;
    if (gm < N_NODES) {
      load8(&A[(size_t)gm * K + k0 + ks], av8);
    } else {
#pragma unroll
      for (int j = 0; j < 8; ++j) av8[j] = 0.f;
    }
    __syncthreads();
#pragma unroll
    for (int j = 0; j < 8; ++j) As[rs][ks + j] = av8[j];
    __syncthreads();

    const float* Bp = B + (size_t)k0 * DIM_H + tx * 8;
#pragma unroll 4
    for (int k = 0; k < 32; ++k) {
      float bv[8];
      load8(Bp + (size_t)k * DIM_H, bv);
      float av[4];
#pragma unroll
      for (int rr = 0; rr < 4; ++rr) av[rr] = As[ty * 4 + rr][k];
#pragma unroll
      for (int rr = 0; rr < 4; ++rr)
#pragma unroll
        for (int cc = 0; cc < 8; ++cc)
          acc[rr][cc] = fmaf(av[rr], bv[cc], acc[rr][cc]);
    }
  }

  float bs[8];
  if (bias) {
    load8(bias + tx * 8, bs);
  } else {
#pragma unroll
    for (int j = 0; j < 8; ++j) bs[j] = 0.f;
  }
#pragma unroll
  for (int rr = 0; rr < 4; ++rr) {
    const int gm = m0 + ty * 4 + rr;
    if (gm < N_NODES) {
      float sc = scale ? scale[gm] : 1.0f;
      float v[8];
#pragma unroll
      for (int cc = 0; cc < 8; ++cc) {
        float t = acc[rr][cc] + bs[cc];
        if (do_relu) t = fmaxf(t, 0.f);
        v[cc] = t * sc;
      }
      float* Cp = &C[(size_t)gm * DIM_H + tx * 8];
      reinterpret_cast<float4*>(Cp)[0] = make_float4(v[0], v[1], v[2], v[3]);
      reinterpret_cast<float4*>(Cp)[1] = make_float4(v[4], v[5], v[6], v[7]);
    }
  }
}

// ---------------------------------------------------------------- CSR gather
__global__ __launch_bounds__(256)
void k_aggr_csr(const int* __restrict__ off, const int* __restrict__ csr,
                const float* __restrict__ t, const float* __restrict__ dinv,
                const float* __restrict__ bias, float* __restrict__ h) {
  int node = blockIdx.x * 4 + (threadIdx.x >> 6);
  if (node >= N_NODES) return;
  int lane = threadIdx.x & 63;
  const float2* t2 = (const float2*)t;
  int start = (node == 0) ? 0 : off[node - 1];
  int end = off[node];
  float2 acc = t2[(size_t)node * 64 + lane];  // self term (prescaled)
  int e = start;
  for (; e + 3 < end; e += 4) {
    int s0 = csr[e], s1 = csr[e + 1], s2 = csr[e + 2], s3 = csr[e + 3];
    float2 v0 = t2[(size_t)s0 * 64 + lane];
    float2 v1 = t2[(size_t)s1 * 64 + lane];
    float2 v2 = t2[(size_t)s2 * 64 + lane];
    float2 v3 = t2[(size_t)s3 * 64 + lane];
    acc.x += (v0.x + v1.x) + (v2.x + v3.x);
    acc.y += (v0.y + v1.y) + (v2.y + v3.y);
  }
  for (; e < end; ++e) {
    int s0 = csr[e];
    float2 v0 = t2[(size_t)s0 * 64 + lane];
    acc.x += v0.x;
    acc.y += v0.y;
  }
  float dn = dinv[node];
  float2 b = ((const float2*)bias)[lane];
  float2 o;
  o.x = b.x + dn * acc.x;
  o.y = b.y + dn * acc.y;
  ((float2*)h)[(size_t)node * 64 + lane] = o;
}

// ------------------------------------------- fallback atomic aggregation
__global__ __launch_bounds__(256)
void k_aggr_init(const float* __restrict__ t, const float* __restrict__ dinv,
                 const float* __restrict__ bias, float* __restrict__ h) {
  int idx = blockIdx.x * 256 + threadIdx.x;
  if (idx < N_NODES * DIM_H) {
    int i = idx >> 7;
    int c = idx & 127;
    float d = dinv[i];
    h[idx] = bias[c] + t[idx] * d * d;
  }
}

__global__ __launch_bounds__(256)
void k_aggr_edges(const int* __restrict__ eidx, const int* __restrict__ flag,
                  const float* __restrict__ t, const float* __restrict__ dinv,
                  float* __restrict__ h) {
  int e = blockIdx.x * 2 + (threadIdx.x >> 7);
  int c = threadIdx.x & 127;
  int is64 = *flag;
  if (e < N_EDGES) {
    unsigned s = (unsigned)get_src(eidx, is64, e);
    unsigned d = (unsigned)get_dst(eidx, is64, e);
    if (s < N_NODES && d < N_NODES) {
      float nrm = dinv[s] * dinv[d];
      unsafeAtomicAdd(&h[(size_t)d * DIM_H + c], t[(size_t)s * DIM_H + c] * nrm);
    }
  }
}

// ---------------------------------------------------------------- head
__global__ __launch_bounds__(256)
void k_head(const float* __restrict__ h, const float* __restrict__ Wh,
            const float* __restrict__ bh, float* __restrict__ out) {
  int node = blockIdx.x * 4 + (threadIdx.x >> 6);
  int lane = threadIdx.x & 63;
  if (node >= N_NODES) return;
  float h0 = h[(size_t)node * DIM_H + lane];
  float h1 = h[(size_t)node * DIM_H + 64 + lane];
  float s0 = h0 * Wh[lane * 2 + 0] + h1 * Wh[(lane + 64) * 2 + 0];
  float s1 = h0 * Wh[lane * 2 + 1] + h1 * Wh[(lane + 64) * 2 + 1];
#pragma unroll
  for (int off = 32; off > 0; off >>= 1) {
    s0 += __shfl_down(s0, off);
    s1 += __shfl_down(s1, off);
  }
  if (lane == 0) {
    reinterpret_cast<float2*>(out)[node] = make_float2(s0 + bh[0], s1 + bh[1]);
  }
}

// ---------------------------------------------------------------- launch
extern "C" void kernel_launch(void* const* d_in, const int* in_sizes, int n_in,
                              void* d_out, int out_size, void* d_ws, size_t ws_size,
                              hipStream_t stream) {
  (void)in_sizes; (void)n_in; (void)out_size;
  const int* eidx = (const int*)d_in[0];
  const float* x  = (const float*)d_in[1];
  const float* Wi = (const float*)d_in[2];
  const float* bi = (const float*)d_in[3];
  const float* W1 = (const float*)d_in[4];
  const float* b1 = (const float*)d_in[5];
  const float* W2 = (const float*)d_in[6];
  const float* b2 = (const float*)d_in[7];
  const float* Wh = (const float*)d_in[8];
  const float* bh = (const float*)d_in[9];
  float* out = (float*)d_out;

  const int gN  = (N_NODES + 255) / 256;
  const int gE  = (N_EDGES + 255) / 256;
  const int gM  = (N_NODES + 63) / 64;
  const int gW  = (N_NODES + 3) / 4;

  char* ws = (char*)d_ws;
  int* flag = (int*)ws;
  int* bsum = (int*)(ws + 512);  // 196 ints, fits in the flag page
  k_detect<<<1, 1024, 0, stream>>>(eidx, flag);

  const size_t need1 = 109866496;
  const size_t need2 = 58405888 + (size_t)N_NODES * DIM_H * 4;

  if (ws_size >= need1) {
    ushort* bfWi = (ushort*)(ws + 4096);
    ushort* bfW1 = (ushort*)(ws + 135168);
    ushort* bfW2 = (ushort*)(ws + 200704);
    int*    off  = (int*)(ws + 266240);
    float*  dinv = (float*)(ws + 666240);
    int*    csr  = (int*)(ws + 1066240);
    float*  bufA = (float*)(ws + 7466496);
    float*  bufB = (float*)(ws + 58666496);

    k_bsplit<<<16, 256, 0, stream>>>(Wi, 8, bfWi);
    k_bsplit<<<8, 256, 0, stream>>>(W1, 4, bfW1);
    k_bsplit<<<8, 256, 0, stream>>>(W2, 4, bfW2);

    k_zero<<<gN, 256, 0, stream>>>(off, N_NODES);
    k_count<<<gE, 256, 0, stream>>>(eidx, flag, off);
    k_dinv<<<gN, 256, 0, stream>>>(off, dinv);
    k_scan1<<<SCAN_NB, SCAN_B, 0, stream>>>(off, bsum);
    k_scan2<<<1, 256, 0, stream>>>(bsum);
    k_scan3<<<SCAN_NB, SCAN_B, 0, stream>>>(off, bsum);
    k_fill<<<gE, 256, 0, stream>>>(eidx, flag, off, csr);

    k_gemm_mfma<DIM_IN><<<gM, 256, 0, stream>>>(x, bfWi, bi, nullptr, bufA, 1);
    k_gemm_mfma<DIM_H><<<gM, 256, 0, stream>>>(bufA, bfW1, nullptr, dinv, bufB, 0);
    k_aggr_csr<<<gW, 256, 0, stream>>>(off, csr, bufB, dinv, b1, bufA);
    k_gemm_mfma<DIM_H><<<gM, 256, 0, stream>>>(bufA, bfW2, nullptr, dinv, bufB, 0);
    k_aggr_csr<<<gW, 256, 0, stream>>>(off, csr, bufB, dinv, b2, bufA);

    k_head<<<gW, 256, 0, stream>>>(bufA, Wh, bh, out);
  } else if (ws_size >= need2) {
    int*   off  = (int*)(ws + 4096);
    float* dinv = (float*)(ws + 404480);
    int*   csr  = (int*)(ws + 804864);
    float* bufA = (float*)(ws + 7205376);
    float* bufB = (float*)(ws + 58405888);

    k_zero<<<gN, 256, 0, stream>>>(off, N_NODES);
    k_count<<<gE, 256, 0, stream>>>(eidx, flag, off);
    k_dinv<<<gN, 256, 0, stream>>>(off, dinv);
    k_scan1<<<SCAN_NB, SCAN_B, 0, stream>>>(off, bsum);
    k_scan2<<<1, 256, 0, stream>>>(bsum);
    k_scan3<<<SCAN_NB, SCAN_B, 0, stream>>>(off, bsum);
    k_fill<<<gE, 256, 0, stream>>>(eidx, flag, off, csr);

    k_gemm<DIM_IN><<<gM, 256, 0, stream>>>(x, Wi, bi, nullptr, bufA, 1);
    k_gemm<DIM_H><<<gM, 256, 0, stream>>>(bufA, W1, nullptr, dinv, bufB, 0);
    k_aggr_csr<<<gW, 256, 0, stream>>>(off, csr, bufB, dinv, b1, bufA);
    k_gemm<DIM_H><<<gM, 256, 0, stream>>>(bufA, W2, nullptr, dinv, bufB, 0);
    k_aggr_csr<<<gW, 256, 0, stream>>>(off, csr, bufB, dinv, b2, bufA);
    k_head<<<gW, 256, 0, stream>>>(bufA, Wh, bh, out);
  } else {
    int*   off  = (int*)(ws + 4096);
    float* dinv = (float*)(ws + 404480);
    float* fbA  = (float*)(ws + 804864);
    float* fbB  = (float*)(ws + 804864 + (size_t)N_NODES * DIM_H * 4);
    const int gNH = (N_NODES * DIM_H + 255) / 256;
    const int gE2 = (N_EDGES + 1) / 2;
    k_zero<<<gN, 256, 0, stream>>>(off, N_NODES);
    k_count<<<gE, 256, 0, stream>>>(eidx, flag, off);
    k_dinv<<<gN, 256, 0, stream>>>(off, dinv);

    k_gemm<DIM_IN><<<gM, 256, 0, stream>>>(x, Wi, bi, nullptr, fbA, 1);
    k_gemm<DIM_H><<<gM, 256, 0, stream>>>(fbA, W1, nullptr, nullptr, fbB, 0);
    k_aggr_init<<<gNH, 256, 0, stream>>>(fbB, dinv, b1, fbA);
    k_aggr_edges<<<gE2, 256, 0, stream>>>(eidx, flag, fbB, dinv, fbA);
    k_gemm<DIM_H><<<gM, 256, 0, stream>>>(fbA, W2, nullptr, nullptr, fbB, 0);
    k_aggr_init<<<gNH, 256, 0, stream>>>(fbB, dinv, b2, fbA);
    k_aggr_edges<<<gE2, 256, 0, stream>>>(eidx, flag, fbB, dinv, fbA);
    k_head<<<gW, 256, 0, stream>>>(fbA, Wh, bh, out);
  }
}

// Round 7
// 615.927 us; speedup vs baseline: 3.2259x; 1.1683x over previous
//
#include <hip/hip_runtime.h>
#include <hip/hip_bf16.h>

#define N_NODES 100000
#define N_EDGES 1600000
#define DIM_IN  256
#define DIM_H   128

#define SCAN_B 512
#define SCAN_NB ((N_NODES + SCAN_B - 1) / SCAN_B)   // 196

typedef __attribute__((ext_vector_type(8))) short short8;
typedef __attribute__((ext_vector_type(4))) float f32x4;

// ------------------------------------------------- edge_index width detect
__global__ __launch_bounds__(1024) void k_detect(const int* __restrict__ e,
                                                 int* __restrict__ flag) {
  __shared__ int s;
  if (threadIdx.x == 0) s = 0;
  __syncthreads();
  atomicOr(&s, e[2 * threadIdx.x + 1]);
  __syncthreads();
  if (threadIdx.x == 0) *flag = (s == 0) ? 1 : 0;
}

__device__ __forceinline__ int get_src(const int* e, int is64, int i) {
  return is64 ? e[2 * i] : e[i];
}
__device__ __forceinline__ int get_dst(const int* e, int is64, int i) {
  return is64 ? e[2 * (N_EDGES + i)] : e[N_EDGES + i];
}

// ---------------------------------------------------------------- degree/CSR
__global__ __launch_bounds__(256) void k_zero(int* __restrict__ p, int n) {
  int i = blockIdx.x * 256 + threadIdx.x;
  if (i < n) p[i] = 0;
}

__global__ __launch_bounds__(256) void k_count(const int* __restrict__ eidx,
                                               const int* __restrict__ flag,
                                               int* __restrict__ off) {
  int e = blockIdx.x * 256 + threadIdx.x;
  int is64 = *flag;
  if (e < N_EDGES) {
    unsigned d = (unsigned)get_dst(eidx, is64, e);
    if (d < N_NODES) atomicAdd(&off[d], 1);
  }
}

__global__ __launch_bounds__(256) void k_dinv(const int* __restrict__ off,
                                              float* __restrict__ dinv) {
  int i = blockIdx.x * 256 + threadIdx.x;
  if (i < N_NODES) dinv[i] = rsqrtf(1.0f + (float)off[i]);
}

// ---- 3-phase parallel exclusive scan ----
__global__ __launch_bounds__(SCAN_B)
void k_scan1(int* __restrict__ off, int* __restrict__ bsum) {
  __shared__ int s[SCAN_B];
  int t = threadIdx.x;
  int i = blockIdx.x * SCAN_B + t;
  int v = (i < N_NODES) ? off[i] : 0;
  s[t] = v;
  __syncthreads();
  for (int d = 1; d < SCAN_B; d <<= 1) {
    int u = (t >= d) ? s[t - d] : 0;
    __syncthreads();
    s[t] += u;
    __syncthreads();
  }
  if (i < N_NODES) off[i] = s[t] - v;
  if (t == SCAN_B - 1) bsum[blockIdx.x] = s[t];
}

__global__ __launch_bounds__(256)
void k_scan2(int* __restrict__ bsum) {
  __shared__ int s[256];
  int t = threadIdx.x;
  int v = (t < SCAN_NB) ? bsum[t] : 0;
  s[t] = v;
  __syncthreads();
  for (int d = 1; d < 256; d <<= 1) {
    int u = (t >= d) ? s[t - d] : 0;
    __syncthreads();
    s[t] += u;
    __syncthreads();
  }
  if (t < SCAN_NB) bsum[t] = s[t] - v;
}

__global__ __launch_bounds__(SCAN_B)
void k_scan3(int* __restrict__ off, const int* __restrict__ bsum) {
  int i = blockIdx.x * SCAN_B + threadIdx.x;
  if (i < N_NODES) off[i] += bsum[blockIdx.x];
}

__global__ __launch_bounds__(256) void k_fill(const int* __restrict__ eidx,
                                              const int* __restrict__ flag,
                                              int* __restrict__ off,
                                              int* __restrict__ csr) {
  int e = blockIdx.x * 256 + threadIdx.x;
  int is64 = *flag;
  if (e < N_EDGES) {
    unsigned s = (unsigned)get_src(eidx, is64, e);
    unsigned d = (unsigned)get_dst(eidx, is64, e);
    if (s < N_NODES && d < N_NODES) {
      int pos = atomicAdd(&off[d], 1);
      csr[pos] = (int)s;
    }
  }
}

// ---------------------------------------------------------------- bf16 utils
__device__ __forceinline__ ushort f2bf(float f) {
  unsigned u = __float_as_uint(f);
  unsigned r = (u + 0x7fffu + ((u >> 16) & 1u)) >> 16;
  return (ushort)r;
}
__device__ __forceinline__ float bf2f(ushort h) {
  return __uint_as_float(((unsigned)h) << 16);
}
__device__ __forceinline__ float bflo(unsigned u) {  // low ushort -> float
  return __uint_as_float(u << 16);
}
__device__ __forceinline__ float bfhi(unsigned u) {  // high ushort -> float
  return __uint_as_float(u & 0xffff0000u);
}
__device__ __forceinline__ unsigned bfpack(float a, float b) {
  return (unsigned)f2bf(a) | ((unsigned)f2bf(b) << 16);
}

__device__ __forceinline__ void load8(const float* p, float* o) {
  float4 a = reinterpret_cast<const float4*>(p)[0];
  float4 b = reinterpret_cast<const float4*>(p)[1];
  o[0] = a.x; o[1] = a.y; o[2] = a.z; o[3] = a.w;
  o[4] = b.x; o[5] = b.y; o[6] = b.z; o[7] = b.w;
}

// Split weight W[K x 128] into MFMA B-fragment planes (hi, lo).
__global__ __launch_bounds__(256)
void k_bsplit(const float* __restrict__ W, const int CH, ushort* __restrict__ outHi) {
  int idx = blockIdx.x * 256 + threadIdx.x;
  if (idx >= CH * 512) return;
  int n  = idx & 15;
  int qq = (idx >> 4) & 3;
  int nt = (idx >> 6) & 7;
  int c  = idx >> 9;
  int col = nt * 16 + n;
  short8 h8, l8;
#pragma unroll
  for (int j = 0; j < 8; ++j) {
    float v = W[(size_t)(c * 32 + qq * 8 + j) * DIM_H + col];
    ushort hb = f2bf(v);
    ushort lb = f2bf(v - bf2f(hb));
    h8[j] = (short)hb;
    l8[j] = (short)lb;
  }
  ((short8*)outHi)[idx] = h8;
  ((short8*)outHi)[CH * 512 + idx] = l8;
}

// ------------------------------------- MFMA GEMM, fp32 A (split), bf16 out
// h1 = relu(x @ Wi + bi) ; 3 MFMAs (hi*hi + hi*lo + lo*hi)
template <int K>
__global__ __launch_bounds__(256)
void k_gemm_x(const float* __restrict__ A, const ushort* __restrict__ Bfrag,
              const float* __restrict__ bias, ushort* __restrict__ C) {
  constexpr int CH = K / 32;
  __shared__ __align__(16) ushort AhiS[256 * 8];
  __shared__ __align__(16) ushort AloS[256 * 8];
  const int tid = threadIdx.x;
  const int m0 = blockIdx.x * 64;
  const int wave = tid >> 6, lane = tid & 63;
  const int m_l = lane & 15, quad = lane >> 4;
  const int rs = tid >> 2, q = tid & 3;

  f32x4 acc[2][4];
#pragma unroll
  for (int i = 0; i < 2; ++i)
#pragma unroll
    for (int j = 0; j < 4; ++j) acc[i][j] = (f32x4){0.f, 0.f, 0.f, 0.f};

  const short8* Bhi8 = (const short8*)Bfrag;
  const short8* Blo8 = Bhi8 + CH * 512;
  short8* Ah8 = (short8*)AhiS;
  short8* Al8 = (short8*)AloS;

  for (int c = 0; c < CH; ++c) {
    float v[8];
    const int gm = m0 + rs;
    if (gm < N_NODES) {
      load8(&A[(size_t)gm * K + c * 32 + q * 8], v);
    } else {
#pragma unroll
      for (int j = 0; j < 8; ++j) v[j] = 0.f;
    }
    short8 h8, l8;
#pragma unroll
    for (int j = 0; j < 8; ++j) {
      ushort hb = f2bf(v[j]);
      ushort lb = f2bf(v[j] - bf2f(hb));
      h8[j] = (short)hb;
      l8[j] = (short)lb;
    }
    __syncthreads();
    const int ent = (rs >> 4) * 64 + q * 16 + (rs & 15);
    Ah8[ent] = h8;
    Al8[ent] = l8;
    __syncthreads();

    short8 ahi[4], alo[4];
#pragma unroll
    for (int mt = 0; mt < 4; ++mt) {
      ahi[mt] = Ah8[mt * 64 + quad * 16 + m_l];
      alo[mt] = Al8[mt * 64 + quad * 16 + m_l];
    }
#pragma unroll
    for (int ntl = 0; ntl < 2; ++ntl) {
      const int bent = ((c * 8 + wave * 2 + ntl) * 4 + quad) * 16 + m_l;
      short8 bhi = Bhi8[bent];
      short8 blo = Blo8[bent];
#pragma unroll
      for (int mt = 0; mt < 4; ++mt) {
        acc[ntl][mt] = __builtin_amdgcn_mfma_f32_16x16x32_bf16(ahi[mt], bhi, acc[ntl][mt], 0, 0, 0);
        acc[ntl][mt] = __builtin_amdgcn_mfma_f32_16x16x32_bf16(ahi[mt], blo, acc[ntl][mt], 0, 0, 0);
        acc[ntl][mt] = __builtin_amdgcn_mfma_f32_16x16x32_bf16(alo[mt], bhi, acc[ntl][mt], 0, 0, 0);
      }
    }
  }

#pragma unroll
  for (int ntl = 0; ntl < 2; ++ntl) {
    const int colg = (wave * 2 + ntl) * 16 + m_l;
    const float bv = bias[colg];
#pragma unroll
    for (int mt = 0; mt < 4; ++mt) {
#pragma unroll
      for (int r = 0; r < 4; ++r) {
        const int rowg = m0 + mt * 16 + quad * 4 + r;
        if (rowg < N_NODES) {
          float t = fmaxf(acc[ntl][mt][r] + bv, 0.f);  // relu
          C[(size_t)rowg * DIM_H + colg] = f2bf(t);
        }
      }
    }
  }
}

// ------------------------------------- MFMA GEMM, bf16 A, bf16 out, row scale
// t = (h @ W) * dinv[row] ; 2 MFMAs (a*bhi + a*blo)
__global__ __launch_bounds__(256)
void k_gemm_h(const ushort* __restrict__ A, const ushort* __restrict__ Bfrag,
              const float* __restrict__ scale, ushort* __restrict__ C) {
  constexpr int K = DIM_H, CH = K / 32;
  __shared__ __align__(16) ushort AS[256 * 8];
  const int tid = threadIdx.x;
  const int m0 = blockIdx.x * 64;
  const int wave = tid >> 6, lane = tid & 63;
  const int m_l = lane & 15, quad = lane >> 4;
  const int rs = tid >> 2, q = tid & 3;

  f32x4 acc[2][4];
#pragma unroll
  for (int i = 0; i < 2; ++i)
#pragma unroll
    for (int j = 0; j < 4; ++j) acc[i][j] = (f32x4){0.f, 0.f, 0.f, 0.f};

  const short8* Bhi8 = (const short8*)Bfrag;
  const short8* Blo8 = Bhi8 + CH * 512;
  short8* A8 = (short8*)AS;

#pragma unroll
  for (int c = 0; c < CH; ++c) {
    short8 h8 = {0, 0, 0, 0, 0, 0, 0, 0};
    const int gm = m0 + rs;
    if (gm < N_NODES)
      h8 = *reinterpret_cast<const short8*>(&A[(size_t)gm * DIM_H + c * 32 + q * 8]);
    __syncthreads();
    A8[(rs >> 4) * 64 + q * 16 + (rs & 15)] = h8;
    __syncthreads();

    short8 a[4];
#pragma unroll
    for (int mt = 0; mt < 4; ++mt) a[mt] = A8[mt * 64 + quad * 16 + m_l];
#pragma unroll
    for (int ntl = 0; ntl < 2; ++ntl) {
      const int bent = ((c * 8 + wave * 2 + ntl) * 4 + quad) * 16 + m_l;
      short8 bhi = Bhi8[bent];
      short8 blo = Blo8[bent];
#pragma unroll
      for (int mt = 0; mt < 4; ++mt) {
        acc[ntl][mt] = __builtin_amdgcn_mfma_f32_16x16x32_bf16(a[mt], bhi, acc[ntl][mt], 0, 0, 0);
        acc[ntl][mt] = __builtin_amdgcn_mfma_f32_16x16x32_bf16(a[mt], blo, acc[ntl][mt], 0, 0, 0);
      }
    }
  }

#pragma unroll
  for (int ntl = 0; ntl < 2; ++ntl) {
    const int colg = (wave * 2 + ntl) * 16 + m_l;
#pragma unroll
    for (int mt = 0; mt < 4; ++mt) {
#pragma unroll
      for (int r = 0; r < 4; ++r) {
        const int rowg = m0 + mt * 16 + quad * 4 + r;
        if (rowg < N_NODES)
          C[(size_t)rowg * DIM_H + colg] = f2bf(acc[ntl][mt][r] * scale[rowg]);
      }
    }
  }
}

// ---------------------------------------------------------------- CSR gather
// t bf16 (prescaled by dinv[row]); h bf16 out.
// h[i] = bias + dinv[i]*(t[i] + sum_{s in in(i)} t[s]); one wave/node, uint/lane.
__global__ __launch_bounds__(256)
void k_aggr_csr(const int* __restrict__ off, const int* __restrict__ csr,
                const ushort* __restrict__ t, const float* __restrict__ dinv,
                const float* __restrict__ bias, ushort* __restrict__ h) {
  int node = blockIdx.x * 4 + (threadIdx.x >> 6);
  if (node >= N_NODES) return;
  int lane = threadIdx.x & 63;
  const unsigned* tu = (const unsigned*)t;
  int start = (node == 0) ? 0 : off[node - 1];
  int end = off[node];
  unsigned su = tu[(size_t)node * 64 + lane];
  float ax = bflo(su), ay = bfhi(su);
  int e = start;
  for (; e + 3 < end; e += 4) {
    int s0 = csr[e], s1 = csr[e + 1], s2 = csr[e + 2], s3 = csr[e + 3];
    unsigned u0 = tu[(size_t)s0 * 64 + lane];
    unsigned u1 = tu[(size_t)s1 * 64 + lane];
    unsigned u2 = tu[(size_t)s2 * 64 + lane];
    unsigned u3 = tu[(size_t)s3 * 64 + lane];
    ax += (bflo(u0) + bflo(u1)) + (bflo(u2) + bflo(u3));
    ay += (bfhi(u0) + bfhi(u1)) + (bfhi(u2) + bfhi(u3));
  }
  for (; e < end; ++e) {
    unsigned u0 = tu[(size_t)csr[e] * 64 + lane];
    ax += bflo(u0);
    ay += bfhi(u0);
  }
  float dn = dinv[node];
  float2 b = ((const float2*)bias)[lane];
  ((unsigned*)h)[(size_t)node * 64 + lane] = bfpack(b.x + dn * ax, b.y + dn * ay);
}

// ---------------------------------------------------------------- head (bf16 h)
__global__ __launch_bounds__(256)
void k_head(const ushort* __restrict__ h, const float* __restrict__ Wh,
            const float* __restrict__ bh, float* __restrict__ out) {
  int node = blockIdx.x * 4 + (threadIdx.x >> 6);
  int lane = threadIdx.x & 63;
  if (node >= N_NODES) return;
  unsigned u = ((const unsigned*)h)[(size_t)node * 64 + lane];
  float f0 = bflo(u), f1 = bfhi(u);  // cols 2*lane, 2*lane+1
  float s0 = f0 * Wh[4 * lane + 0] + f1 * Wh[4 * lane + 2];
  float s1 = f0 * Wh[4 * lane + 1] + f1 * Wh[4 * lane + 3];
#pragma unroll
  for (int off = 32; off > 0; off >>= 1) {
    s0 += __shfl_down(s0, off);
    s1 += __shfl_down(s1, off);
  }
  if (lane == 0) {
    reinterpret_cast<float2*>(out)[node] = make_float2(s0 + bh[0], s1 + bh[1]);
  }
}

// ---------------------------------------------------------------- fp32 fallback GEMM
template <int K>
__global__ __launch_bounds__(256)
void k_gemm(const float* __restrict__ A, const float* __restrict__ B,
            const float* __restrict__ bias, const float* __restrict__ scale,
            float* __restrict__ C, const int do_relu) {
  __shared__ float As[64][33];
  const int tid = threadIdx.x;
  const int tx = tid & 15;
  const int ty = tid >> 4;
  const int m0 = blockIdx.x * 64;

  float acc[4][8];
#pragma unroll
  for (int i = 0; i < 4; ++i)
#pragma unroll
    for (int j = 0; j < 8; ++j) acc[i][j] = 0.f;

  const int rs = tid >> 2;
  const int ks = (tid & 3) * 8;

  for (int k0 = 0; k0 < K; k0 += 32) {
    float av8[8];
    const int gm = m0 + rs;
    if (gm < N_NODES) {
      load8(&A[(size_t)gm * K + k0 + ks], av8);
    } else {
#pragma unroll
      for (int j = 0; j < 8; ++j) av8[j] = 0.f;
    }
    __syncthreads();
#pragma unroll
    for (int j = 0; j < 8; ++j) As[rs][ks + j] = av8[j];
    __syncthreads();

    const float* Bp = B + (size_t)k0 * DIM_H + tx * 8;
#pragma unroll 4
    for (int k = 0; k < 32; ++k) {
      float bv[8];
      load8(Bp + (size_t)k * DIM_H, bv);
      float av[4];
#pragma unroll
      for (int rr = 0; rr < 4; ++rr) av[rr] = As[ty * 4 + rr][k];
#pragma unroll
      for (int rr = 0; rr < 4; ++rr)
#pragma unroll
        for (int cc = 0; cc < 8; ++cc)
          acc[rr][cc] = fmaf(av[rr], bv[cc], acc[rr][cc]);
    }
  }

  float bs[8];
  if (bias) {
    load8(bias + tx * 8, bs);
  } else {
#pragma unroll
    for (int j = 0; j < 8; ++j) bs[j] = 0.f;
  }
#pragma unroll
  for (int rr = 0; rr < 4; ++rr) {
    const int gm = m0 + ty * 4 + rr;
    if (gm < N_NODES) {
      float sc = scale ? scale[gm] : 1.0f;
      float v[8];
#pragma unroll
      for (int cc = 0; cc < 8; ++cc) {
        float t = acc[rr][cc] + bs[cc];
        if (do_relu) t = fmaxf(t, 0.f);
        v[cc] = t * sc;
      }
      float* Cp = &C[(size_t)gm * DIM_H + tx * 8];
      reinterpret_cast<float4*>(Cp)[0] = make_float4(v[0], v[1], v[2], v[3]);
      reinterpret_cast<float4*>(Cp)[1] = make_float4(v[4], v[5], v[6], v[7]);
    }
  }
}

// fp32 CSR gather (fallback tier)
__global__ __launch_bounds__(256)
void k_aggr_csr_f32(const int* __restrict__ off, const int* __restrict__ csr,
                    const float* __restrict__ t, const float* __restrict__ dinv,
                    const float* __restrict__ bias, float* __restrict__ h) {
  int node = blockIdx.x * 4 + (threadIdx.x >> 6);
  if (node >= N_NODES) return;
  int lane = threadIdx.x & 63;
  const float2* t2 = (const float2*)t;
  int start = (node == 0) ? 0 : off[node - 1];
  int end = off[node];
  float2 acc = t2[(size_t)node * 64 + lane];
  int e = start;
  for (; e + 3 < end; e += 4) {
    int s0 = csr[e], s1 = csr[e + 1], s2 = csr[e + 2], s3 = csr[e + 3];
    float2 v0 = t2[(size_t)s0 * 64 + lane];
    float2 v1 = t2[(size_t)s1 * 64 + lane];
    float2 v2 = t2[(size_t)s2 * 64 + lane];
    float2 v3 = t2[(size_t)s3 * 64 + lane];
    acc.x += (v0.x + v1.x) + (v2.x + v3.x);
    acc.y += (v0.y + v1.y) + (v2.y + v3.y);
  }
  for (; e < end; ++e) {
    float2 v0 = t2[(size_t)csr[e] * 64 + lane];
    acc.x += v0.x;
    acc.y += v0.y;
  }
  float dn = dinv[node];
  float2 b = ((const float2*)bias)[lane];
  ((float2*)h)[(size_t)node * 64 + lane] =
      make_float2(b.x + dn * acc.x, b.y + dn * acc.y);
}

__global__ __launch_bounds__(256)
void k_head_f32(const float* __restrict__ h, const float* __restrict__ Wh,
                const float* __restrict__ bh, float* __restrict__ out) {
  int node = blockIdx.x * 4 + (threadIdx.x >> 6);
  int lane = threadIdx.x & 63;
  if (node >= N_NODES) return;
  float h0 = h[(size_t)node * DIM_H + lane];
  float h1 = h[(size_t)node * DIM_H + 64 + lane];
  float s0 = h0 * Wh[lane * 2 + 0] + h1 * Wh[(lane + 64) * 2 + 0];
  float s1 = h0 * Wh[lane * 2 + 1] + h1 * Wh[(lane + 64) * 2 + 1];
#pragma unroll
  for (int off = 32; off > 0; off >>= 1) {
    s0 += __shfl_down(s0, off);
    s1 += __shfl_down(s1, off);
  }
  if (lane == 0) {
    reinterpret_cast<float2*>(out)[node] = make_float2(s0 + bh[0], s1 + bh[1]);
  }
}

// ---------------------------------------------------------------- launch
extern "C" void kernel_launch(void* const* d_in, const int* in_sizes, int n_in,
                              void* d_out, int out_size, void* d_ws, size_t ws_size,
                              hipStream_t stream) {
  (void)in_sizes; (void)n_in; (void)out_size;
  const int* eidx = (const int*)d_in[0];
  const float* x  = (const float*)d_in[1];
  const float* Wi = (const float*)d_in[2];
  const float* bi = (const float*)d_in[3];
  const float* W1 = (const float*)d_in[4];
  const float* b1 = (const float*)d_in[5];
  const float* W2 = (const float*)d_in[6];
  const float* b2 = (const float*)d_in[7];
  const float* Wh = (const float*)d_in[8];
  const float* bh = (const float*)d_in[9];
  float* out = (float*)d_out;

  const int gN  = (N_NODES + 255) / 256;
  const int gE  = (N_EDGES + 255) / 256;
  const int gM  = (N_NODES + 63) / 64;
  const int gW  = (N_NODES + 3) / 4;

  char* ws = (char*)d_ws;
  int* flag = (int*)ws;
  int* bsum = (int*)(ws + 512);
  k_detect<<<1, 1024, 0, stream>>>(eidx, flag);

  // tier 1 (bf16 activations): ends at 58,666,496 bytes
  const size_t need1 = 58666496;
  // tier 2 (fp32 CSR path): ~109.6 MB
  const size_t need2 = 58405888 + (size_t)N_NODES * DIM_H * 4;

  if (ws_size >= need1) {
    ushort* bfWi = (ushort*)(ws + 4096);       // 128 KB (2 planes)
    ushort* bfW1 = (ushort*)(ws + 135168);     // 64 KB
    ushort* bfW2 = (ushort*)(ws + 200704);     // 64 KB
    int*    off  = (int*)(ws + 266240);
    float*  dinv = (float*)(ws + 666240);
    int*    csr  = (int*)(ws + 1066240);       // 6.4 MB
    ushort* bufA = (ushort*)(ws + 7466496);    // 25.6 MB bf16
    ushort* bufB = (ushort*)(ws + 33066496);   // 25.6 MB bf16

    k_bsplit<<<16, 256, 0, stream>>>(Wi, 8, bfWi);
    k_bsplit<<<8, 256, 0, stream>>>(W1, 4, bfW1);
    k_bsplit<<<8, 256, 0, stream>>>(W2, 4, bfW2);

    k_zero<<<gN, 256, 0, stream>>>(off, N_NODES);
    k_count<<<gE, 256, 0, stream>>>(eidx, flag, off);
    k_dinv<<<gN, 256, 0, stream>>>(off, dinv);
    k_scan1<<<SCAN_NB, SCAN_B, 0, stream>>>(off, bsum);
    k_scan2<<<1, 256, 0, stream>>>(bsum);
    k_scan3<<<SCAN_NB, SCAN_B, 0, stream>>>(off, bsum);
    k_fill<<<gE, 256, 0, stream>>>(eidx, flag, off, csr);

    // h1 = relu(x @ Wi + bi)           [bf16]
    k_gemm_x<DIM_IN><<<gM, 256, 0, stream>>>(x, bfWi, bi, bufA);
    // layer 1: t = (h1 @ W1) * dinv ; h2 = b1 + dinv*(self + gather)
    k_gemm_h<<<gM, 256, 0, stream>>>(bufA, bfW1, dinv, bufB);
    k_aggr_csr<<<gW, 256, 0, stream>>>(off, csr, bufB, dinv, b1, bufA);
    // layer 2
    k_gemm_h<<<gM, 256, 0, stream>>>(bufA, bfW2, dinv, bufB);
    k_aggr_csr<<<gW, 256, 0, stream>>>(off, csr, bufB, dinv, b2, bufA);

    k_head<<<gW, 256, 0, stream>>>(bufA, Wh, bh, out);
  } else if (ws_size >= need2) {
    int*   off  = (int*)(ws + 4096);
    float* dinv = (float*)(ws + 404480);
    int*   csr  = (int*)(ws + 804864);
    float* bufA = (float*)(ws + 7205376);
    float* bufB = (float*)(ws + 58405888);

    k_zero<<<gN, 256, 0, stream>>>(off, N_NODES);
    k_count<<<gE, 256, 0, stream>>>(eidx, flag, off);
    k_dinv<<<gN, 256, 0, stream>>>(off, dinv);
    k_scan1<<<SCAN_NB, SCAN_B, 0, stream>>>(off, bsum);
    k_scan2<<<1, 256, 0, stream>>>(bsum);
    k_scan3<<<SCAN_NB, SCAN_B, 0, stream>>>(off, bsum);
    k_fill<<<gE, 256, 0, stream>>>(eidx, flag, off, csr);

    k_gemm<DIM_IN><<<gM, 256, 0, stream>>>(x, Wi, bi, nullptr, bufA, 1);
    k_gemm<DIM_H><<<gM, 256, 0, stream>>>(bufA, W1, nullptr, dinv, bufB, 0);
    k_aggr_csr_f32<<<gW, 256, 0, stream>>>(off, csr, bufB, dinv, b1, bufA);
    k_gemm<DIM_H><<<gM, 256, 0, stream>>>(bufA, W2, nullptr, dinv, bufB, 0);
    k_aggr_csr_f32<<<gW, 256, 0, stream>>>(off, csr, bufB, dinv, b2, bufA);
    k_head_f32<<<gW, 256, 0, stream>>>(bufA, Wh, bh, out);
  }
}